// Round 7
// baseline (57.898 us; speedup 1.0000x reference)
//
#include <hip/hip_runtime.h>

#define H 1024
#define W 1024
#define OH 1016
#define OW 1016
#define NB 16
#define BAND 8             // output rows per wave; 127*8 = 1016 exact
#define STEPS (BAND + 8)   // 16 input rows swept per wave
#define WCOLS 248          // useful output cols per 64-lane wave
#define NWX 5              // ceil(1016 / 248)
#define NBANDS 127
#define WPB 2              // waves per block (128 threads)

typedef float vfloat4 __attribute__((ext_vector_type(4)));

__global__ __launch_bounds__(128)
void cov_kernel(const float* __restrict__ xg,
                const float* __restrict__ yg,
                float* __restrict__ outg) {
    const int t    = threadIdx.x & 63;             // lane 0..63
    const int wv   = threadIdx.x >> 6;             // wave in block
    const int band = blockIdx.y * WPB + wv;        // row band
    if (band >= NBANDS) return;
    const int wx   = blockIdx.x;                   // column group
    const int img  = blockIdx.z;

    const int cb = wx * WCOLS + 4 * t;             // lane's first column
    const int O  = band * BAND;                    // first output row of band
    const bool lok = (cb <= W - 4);
    const bool sok = (t <= 61) && (cb <= OW - 4);

    const float* xb = xg + (size_t)img * H * W;
    const float* yb = yg + (size_t)img * H * W;
    float* ob = outg + (size_t)img * OH * OW;

    const float4 z4 = make_float4(0.f, 0.f, 0.f, 0.f);
    float4 hx[5], hy[5], hp[5];
    #pragma unroll
    for (int i = 0; i < 5; ++i) { hx[i] = z4; hy[i] = z4; hp[i] = z4; }
    float4 csx = z4, csy = z4, ps = z4;
    const float k = 1.0f / 25.0f;

    // depth-2 prefetch (rows s, s+1 pending; statically indexed after unroll)
    float4 pnx[2], pny[2];
    #pragma unroll
    for (int i = 0; i < 2; ++i) {
        const int r = O + i;                       // always < H (BAND=8 exact tiling)
        float4 vx = z4, vy = z4;
        if (lok) {
            vx = *reinterpret_cast<const float4*>(xb + (size_t)r * W + cb);
            vy = *reinterpret_cast<const float4*>(yb + (size_t)r * W + cb);
        }
        pnx[i] = vx; pny[i] = vy;
    }

    #pragma unroll
    for (int s = 0; s < STEPS; ++s) {
        const float4 nx = pnx[s & 1];
        const float4 ny = pny[s & 1];
        if (s + 2 < STEPS) {                        // issue load for row s+2
            const int r = O + s + 2;                // max 126*8+15 = 1023 < H
            float4 vx = z4, vy = z4;
            if (lok) {
                vx = *reinterpret_cast<const float4*>(xb + (size_t)r * W + cb);
                vy = *reinterpret_cast<const float4*>(yb + (size_t)r * W + cb);
            }
            pnx[s & 1] = vx; pny[s & 1] = vy;
        }

        const int ph = s % 5;
        csx.x += nx.x - hx[ph].x; csx.y += nx.y - hx[ph].y;
        csx.z += nx.z - hx[ph].z; csx.w += nx.w - hx[ph].w;
        csy.x += ny.x - hy[ph].x; csy.y += ny.y - hy[ph].y;
        csy.z += ny.z - hy[ph].z; csy.w += ny.w - hy[ph].w;
        hx[ph] = nx; hy[ph] = ny;

        if (s >= 4) {
            const int pc = (ph + 3) % 5;            // slot of center row r-2
            float bx0 = __shfl_down(csx.x, 1), bx1 = __shfl_down(csx.y, 1);
            float bx2 = __shfl_down(csx.z, 1), bx3 = __shfl_down(csx.w, 1);
            float by0 = __shfl_down(csy.x, 1), by1 = __shfl_down(csy.y, 1);
            float by2 = __shfl_down(csy.z, 1), by3 = __shfl_down(csy.w, 1);
            float cx2 = __shfl_down(hx[pc].x, 1), cx3 = __shfl_down(hx[pc].y, 1);
            float cy2 = __shfl_down(hy[pc].x, 1), cy3 = __shfl_down(hy[pc].y, 1);

            float sx0 = csx.x + csx.y + csx.z + csx.w + bx0;
            float sx1 = sx0 - csx.x + bx1;
            float sx2 = sx1 - csx.y + bx2;
            float sx3 = sx2 - csx.z + bx3;
            float sy0 = csy.x + csy.y + csy.z + csy.w + by0;
            float sy1 = sy0 - csy.x + by1;
            float sy2 = sy1 - csy.y + by2;
            float sy3 = sy2 - csy.z + by3;

            float4 p;
            p.x = (hx[pc].z - sx0 * k) * (hy[pc].z - sy0 * k);
            p.y = (hx[pc].w - sx1 * k) * (hy[pc].w - sy1 * k);
            p.z = (cx2      - sx2 * k) * (cy2      - sy2 * k);
            p.w = (cx3      - sx3 * k) * (cy3      - sy3 * k);

            const int pp = (s + 1) % 5;
            ps.x += p.x - hp[pp].x; ps.y += p.y - hp[pp].y;
            ps.z += p.z - hp[pp].z; ps.w += p.w - hp[pp].w;
            hp[pp] = p;

            if (s >= 8) {
                float bp0 = __shfl_down(ps.x, 1), bp1 = __shfl_down(ps.y, 1);
                float bp2 = __shfl_down(ps.z, 1), bp3 = __shfl_down(ps.w, 1);
                float s0 = ps.x + ps.y + ps.z + ps.w + bp0;
                float s1 = s0 - ps.x + bp1;
                float s2 = s1 - ps.y + bp2;
                float s3 = s2 - ps.z + bp3;
                const int o = O + s - 8;            // 0..1015, no guard needed
                if (sok) {
                    vfloat4 ov = { s0 * k, s1 * k, s2 * k, s3 * k };
                    __builtin_nontemporal_store(ov,
                        reinterpret_cast<vfloat4*>(ob + (size_t)o * OW + cb));
                }
            }
        }
    }
}

extern "C" void kernel_launch(void* const* d_in, const int* in_sizes, int n_in,
                              void* d_out, int out_size, void* d_ws, size_t ws_size,
                              hipStream_t stream) {
    const float* x = (const float*)d_in[0];
    const float* y = (const float*)d_in[1];
    float* out = (float*)d_out;

    dim3 grid(NWX, (NBANDS + WPB - 1) / WPB, NB);  // 5 x 64 x 16 = 5120 blocks x 2 waves
    dim3 block(WPB * 64);
    cov_kernel<<<grid, block, 0, stream>>>(x, y, out);
}